// Round 4
// baseline (335.352 us; speedup 1.0000x reference)
//
#include <hip/hip_runtime.h>

// Problem constants (from reference setup_inputs)
#define BB 32
#define LL 4
#define SS 512
#define DD 768
#define D4 (DD / 4)   // 192 float4 lanes per row
#define GG 24         // NUM_SEGMENTS
#define WPB 8         // words per block in kernel A
#define NCHUNK (SS / WPB)  // 64 word-chunks per batch row

typedef float floatx4 __attribute__((ext_vector_type(4)));

#define WB_STRIDE (SS + 1)

// ---------------------------------------------------------------------------
// Kernel P: wb[b][v] = lower_bound(tg_row, v) for v in 0..SS.
// Word slot w owns token range [wb[w], wb[w+1]). LDS-resident binary search.
// ---------------------------------------------------------------------------
__global__ __launch_bounds__(SS) void bounds_kernel(
    const int* __restrict__ tg, int* __restrict__ wb)
{
    __shared__ int ltg[SS];
    const int b = blockIdx.x;
    const int t = threadIdx.x;
    ltg[t] = tg[b * SS + t];
    __syncthreads();

    int v = t, lo = 0, hi = SS;
    while (lo < hi) { int m = (lo + hi) >> 1; if (ltg[m] < v) lo = m + 1; else hi = m; }
    wb[b * WB_STRIDE + t] = lo;
    if (t == 0) wb[b * WB_STRIDE + SS] = SS;  // lower_bound(·, 512) = SS (ids < 300)
}

// ---------------------------------------------------------------------------
// Kernel A: per block (chunk c, batch b) handle word slots [8c, 8c+8):
//   word[b,w,:] = sum_{s in [wb[w],wb[w+1])} sum_l emb[b,l,s,:]   (plain store,
//   every slot written exactly once -> poison-safe, zero for empty slots)
//   seg[b, sg[b,w], :] += word sum   (HW fp32 atomic; seg pre-zeroed by memset)
// All bounds are wave-uniform scalar loads; emb loads are a long independent
// stream (8 words x ~1.7 tokens x 4 layers x 16B/lane) -> deep ILP, balanced.
// ---------------------------------------------------------------------------
__global__ __launch_bounds__(D4) void word_agg_kernel(
    const floatx4* __restrict__ emb, const int* __restrict__ wb,
    const int* __restrict__ sgids, floatx4* __restrict__ word,
    float* __restrict__ seg)
{
    const int c = blockIdx.x;
    const int b = blockIdx.y;
    const int w0 = c * WPB;
    const int d = threadIdx.x;
    const int* wrow = wb + b * WB_STRIDE + w0;

    for (int wi = 0; wi < WPB; ++wi) {
        const int w = w0 + wi;
        const int lo = wrow[wi];
        const int hi = wrow[wi + 1];

        floatx4 acc = (floatx4)(0.f);
        for (int s = lo; s < hi; ++s) {
#pragma unroll
            for (int l = 0; l < LL; ++l) {
                acc += __builtin_nontemporal_load(
                    &emb[((size_t)((b * LL + l) * SS + s)) * D4 + d]);
            }
        }
        __builtin_nontemporal_store(acc, &word[((size_t)(b * SS + w)) * D4 + d]);

        if (hi > lo) {  // empty slots contribute zero to their segment -> skip
            const int t = sgids[b * SS + w];  // segment id of word position w
            float* sp = seg + ((size_t)(b * GG + t)) * DD + d * 4;
            unsafeAtomicAdd(sp + 0, acc.x);
            unsafeAtomicAdd(sp + 1, acc.y);
            unsafeAtomicAdd(sp + 2, acc.z);
            unsafeAtomicAdd(sp + 3, acc.w);
        }
    }
}

// ---------------------------------------------------------------------------
// Kernel C: sent[b,:] = (1/512) * sum_t seg[b,t,:]  (segment_sum over all 512
// padded word slots partitions them across segments), plus
// seg_mask[b,j] = (j >= sg[b,511]+1) as 0/1 floats (sorted -> last elem = max).
// ---------------------------------------------------------------------------
__global__ __launch_bounds__(D4) void sent_mask_kernel(
    const floatx4* __restrict__ seg, const int* __restrict__ sg,
    floatx4* __restrict__ sent, float* __restrict__ mask)
{
    const int b = blockIdx.x;
    const int d = threadIdx.x;

    floatx4 acc = (floatx4)(0.f);
#pragma unroll
    for (int t = 0; t < GG; ++t) {
        acc += seg[((size_t)(b * GG + t)) * D4 + d];
    }
    acc *= (1.0f / (float)SS);
    sent[(size_t)b * D4 + d] = acc;

    if (d < GG) {
        const int seg_num = sg[b * SS + (SS - 1)] + 1;
        mask[b * GG + d] = (d >= seg_num) ? 1.0f : 0.0f;
    }
}

extern "C" void kernel_launch(void* const* d_in, const int* in_sizes, int n_in,
                              void* d_out, int out_size, void* d_ws, size_t ws_size,
                              hipStream_t stream) {
    const float* emb = (const float*)d_in[0];           // [32,4,512,768] fp32
    const int*   tg  = (const int*)d_in[1];             // [32,512]
    const int*   sg  = (const int*)d_in[2];             // [32,512]

    float* out  = (float*)d_out;
    float* word = out;                                   // [32,512,768]
    float* sent = word + (size_t)BB * SS * DD;           // [32,768]
    float* seg  = sent + (size_t)BB * DD;                // [32,24,768]
    float* mask = seg  + (size_t)BB * GG * DD;           // [32,24]

    int* wb = (int*)d_ws;                                // [32][513]

    // seg is accumulated with atomics -> zero it (d_out arrives poisoned 0xAA)
    hipMemsetAsync(seg, 0, (size_t)BB * GG * DD * sizeof(float), stream);
    bounds_kernel<<<BB, SS, 0, stream>>>(tg, wb);
    word_agg_kernel<<<dim3(NCHUNK, BB), D4, 0, stream>>>(
        (const floatx4*)emb, wb, sg, (floatx4*)word, seg);
    sent_mask_kernel<<<BB, D4, 0, stream>>>((const floatx4*)seg, sg, (floatx4*)sent, mask);
}

// Round 5
// 297.364 us; speedup vs baseline: 1.1278x; 1.1278x over previous
//
#include <hip/hip_runtime.h>

// Problem constants (from reference setup_inputs)
#define BB 32
#define LL 4
#define SS 512
#define DD 768
#define D4 (DD / 4)   // 192 float4 lanes per row
#define GG 24         // NUM_SEGMENTS

// Native clang vector type — required for __builtin_nontemporal_load
typedef float floatx4 __attribute__((ext_vector_type(4)));

// Workspace layout (ints): word_bounds[BB][SS+1], seg_bounds[BB][GG+1]
#define WB_STRIDE (SS + 1)
#define SB_STRIDE (GG + 1)

// ---------------------------------------------------------------------------
// Kernel P: precompute lower-bound boundaries for both id arrays, per batch.
// One block per b; ids cached in LDS so each 9-step binary search is LDS-only.
// wb[b][v] = lower_bound(tg_row, v) for v in 0..512  (word g owns [wb[g], wb[g+1]))
// sb[b][v] = lower_bound(sg_row, v) for v in 0..24   (seg  t owns [sb[t], sb[t+1]))
// ---------------------------------------------------------------------------
__global__ __launch_bounds__(SS) void bounds_kernel(
    const int* __restrict__ tg, const int* __restrict__ sg,
    int* __restrict__ wb, int* __restrict__ sb)
{
    __shared__ int ltg[SS];
    __shared__ int lsg[SS];
    const int b = blockIdx.x;
    const int t = threadIdx.x;
    ltg[t] = tg[b * SS + t];
    lsg[t] = sg[b * SS + t];
    __syncthreads();

    // lower_bound of value v=t in ltg
    {
        int v = t, lo = 0, hi = SS;
        while (lo < hi) { int m = (lo + hi) >> 1; if (ltg[m] < v) lo = m + 1; else hi = m; }
        wb[b * WB_STRIDE + t] = lo;
        if (t == 0) wb[b * WB_STRIDE + SS] = SS;
    }
    // lower_bound of value v=t in lsg, for t in 0..GG
    if (t <= GG) {
        int v = t, lo = 0, hi = SS;
        while (lo < hi) { int m = (lo + hi) >> 1; if (lsg[m] < v) lo = m + 1; else hi = m; }
        sb[b * SB_STRIDE + t] = lo;
    }
}

// ---------------------------------------------------------------------------
// Kernel A: word_embeddings[b,g,:] = sum_{s in [wb[g],wb[g+1])} sum_l emb[b,l,s,:]
// One block per (g,b); 192 threads = one float4 lane each. Bounds are two
// block-uniform loads (L2-resident). emb loads are nontemporal (read-once,
// 201 MB — don't evict the word tensor kernel B re-reads). word store is a
// plain (cached) store so kernel B hits L2/L3.
// ---------------------------------------------------------------------------
__global__ __launch_bounds__(D4) void word_agg_kernel(
    const floatx4* __restrict__ emb, const int* __restrict__ wb, floatx4* __restrict__ word)
{
    const int g = blockIdx.x;
    const int b = blockIdx.y;
    const int lo = wb[b * WB_STRIDE + g];
    const int hi = wb[b * WB_STRIDE + g + 1];
    const int d = threadIdx.x;

    floatx4 acc = (floatx4)(0.f);
    for (int s = lo; s < hi; ++s) {
#pragma unroll
        for (int l = 0; l < LL; ++l) {
            floatx4 v = __builtin_nontemporal_load(
                &emb[((size_t)((b * LL + l) * SS + s)) * D4 + d]);
            acc += v;
        }
    }
    word[((size_t)(b * SS + g)) * D4 + d] = acc;
}

// ---------------------------------------------------------------------------
// Kernel B: seg_embeddings[b,t,:] = sum_{g in [sb[t],sb[t+1])} word[b,g,:]
// ---------------------------------------------------------------------------
__global__ __launch_bounds__(D4) void seg_agg_kernel(
    const floatx4* __restrict__ word, const int* __restrict__ sb, floatx4* __restrict__ seg)
{
    const int t = blockIdx.x;
    const int b = blockIdx.y;
    const int lo = sb[b * SB_STRIDE + t];
    const int hi = sb[b * SB_STRIDE + t + 1];
    const int d = threadIdx.x;

    floatx4 acc = (floatx4)(0.f);
    for (int g = lo; g < hi; ++g) {
        acc += word[((size_t)(b * SS + g)) * D4 + d];
    }
    seg[((size_t)(b * GG + t)) * D4 + d] = acc;
}

// ---------------------------------------------------------------------------
// Kernel C: sent_embeddings[b,:] = (1/512) * sum_t seg[b,t,:]  (segment_sum over
// all 512 padded word slots partitions them across segments), plus
// seg_mask[b,j] = (j >= sg[b,511]+1) as 0/1 floats (sorted -> last elem is max).
// ---------------------------------------------------------------------------
__global__ __launch_bounds__(D4) void sent_mask_kernel(
    const floatx4* __restrict__ seg, const int* __restrict__ sg,
    floatx4* __restrict__ sent, float* __restrict__ mask)
{
    const int b = blockIdx.x;
    const int d = threadIdx.x;

    floatx4 acc = (floatx4)(0.f);
#pragma unroll
    for (int t = 0; t < GG; ++t) {
        acc += seg[((size_t)(b * GG + t)) * D4 + d];
    }
    acc *= (1.0f / (float)SS);
    sent[(size_t)b * D4 + d] = acc;

    if (d < GG) {
        const int seg_num = sg[b * SS + (SS - 1)] + 1;
        mask[b * GG + d] = (d >= seg_num) ? 1.0f : 0.0f;
    }
}

extern "C" void kernel_launch(void* const* d_in, const int* in_sizes, int n_in,
                              void* d_out, int out_size, void* d_ws, size_t ws_size,
                              hipStream_t stream) {
    const float* emb = (const float*)d_in[0];           // [32,4,512,768] fp32
    const int*   tg  = (const int*)d_in[1];             // [32,512]
    const int*   sg  = (const int*)d_in[2];             // [32,512]

    float* out  = (float*)d_out;
    float* word = out;                                   // [32,512,768]
    float* sent = word + (size_t)BB * SS * DD;           // [32,768]
    float* seg  = sent + (size_t)BB * DD;                // [32,24,768]
    float* mask = seg  + (size_t)BB * GG * DD;           // [32,24]

    int* wb = (int*)d_ws;                                // [32][513]
    int* sb = wb + BB * WB_STRIDE;                       // [32][25]

    bounds_kernel<<<BB, SS, 0, stream>>>(tg, sg, wb, sb);
    word_agg_kernel<<<dim3(SS, BB), D4, 0, stream>>>((const floatx4*)emb, wb, (floatx4*)word);
    seg_agg_kernel<<<dim3(GG, BB), D4, 0, stream>>>((const floatx4*)word, sb, (floatx4*)seg);
    sent_mask_kernel<<<BB, D4, 0, stream>>>((const floatx4*)seg, sg, (floatx4*)sent, mask);
}